// Round 12
// baseline (80.030 us; speedup 1.0000x reference)
//
#include <hip/hip_runtime.h>

// ============================================================================
// PGALoss, analytically reduced:
//   per-point loss = sqrt(1 + d^2) + d,  d = NN distance
//   out = 0.5 * sum_dir clip((mean loss - 1)/2, 0, 1)
// d^2 = min_p(||p||^2 - 2 q.p) + ||q||^2   via bf16 hi/lo-split MFMA (R10)
//
// R12: SINGLE fused kernel (2 memsets + 1 dispatch). Each block:
//   1) redundantly preps its 1024-point A-chunk into LDS (padded, b128-clean)
//   2) builds its per-lane B-fragments in registers from raw queries
//   3) 32-tile MFMA loop, in-lane min (v_min3), shfl_xor(32) merge
//   4) atomicMin into d2min
//   5) last block (counter) does the deterministic f64 tree-reduce + out[0]
// Disambiguates the ~25us mystery floor: per-node overhead vs in-kernel stall.
// ============================================================================

typedef short short8 __attribute__((ext_vector_type(8)));
typedef float f32x16 __attribute__((ext_vector_type(16)));

#define PPB      1024            // points per block
#define LDS_HALF 576             // 32 rows * 16B + 4 * 16B pad
#define LDS_TILE 1152            // two k-halves

__device__ __forceinline__ unsigned short bf16h(float f) {
    unsigned u = __float_as_uint(f);
    return (unsigned short)((u + 0x7fffu + ((u >> 16) & 1u)) >> 16);
}
__device__ __forceinline__ float bf16v(unsigned short h) {
    return __uint_as_float((unsigned)h << 16);
}

__global__ __launch_bounds__(256, 4)
void fused_kernel(const float* __restrict__ src, const float* __restrict__ tgt,
                  unsigned* __restrict__ d2min, unsigned* __restrict__ counter,
                  float* __restrict__ out, int N) {
    __shared__ __align__(16) unsigned char Alds[32 * LDS_TILE];  // 36 KB

    const int t   = threadIdx.x;
    const int l   = t & 63, w = t >> 6;
    const int nqc = N >> 8;                  // 32 query chunks (256 q each)
    const int PSL = N / PPB;                 // 8 point chunks
    const int bpt = nqc * PSL;               // 256 blocks per task
    const int task = blockIdx.x / bpt;       // 0..3 = s0,s1,t0,t1
    const int rem  = blockIdx.x % bpt;
    const int qc = rem / PSL, pc = rem % PSL;

    // ---- 1) A-prep: 1024 points of cloud (task^2), chunk pc -> LDS ----
    const int pcloud = task ^ 2;
    const float* pRaw = (pcloud < 2 ? src : tgt)
                        + (size_t)3 * ((size_t)(pcloud & 1) * N + (size_t)pc * PPB);
    #pragma unroll
    for (int k = 0; k < 4; ++k) {
        const int j = t + k * 256;           // local point index 0..1023
        const float x = pRaw[3*j], y = pRaw[3*j+1], z = pRaw[3*j+2];
        const float pp = x*x + y*y + z*z;
        unsigned short A16[16];
        const float p3[3] = {x, y, z};
        #pragma unroll
        for (int d = 0; d < 3; ++d) {
            const float m2 = -2.0f * p3[d];
            const unsigned short th = bf16h(m2);
            A16[d] = th; A16[4+d] = th; A16[8+d] = bf16h(m2 - bf16v(th));
        }
        const unsigned short pph = bf16h(pp);
        A16[3] = pph; A16[7] = bf16h(pp - bf16v(pph)); A16[11] = 0;
        A16[12] = A16[13] = A16[14] = A16[15] = 0;
        const int tile = j >> 5, r = j & 31;
        unsigned char* base = Alds + tile * LDS_TILE + r * 16 + (r >> 3) * 16;
        *(short8*)(base)            = *(const short8*)(A16);      // k 0..7
        *(short8*)(base + LDS_HALF) = *(const short8*)(A16 + 8);  // k 8..15
    }

    // ---- 2) B-fragments in registers (lane owns cols l&31 of 2 B-tiles) ----
    const int col = l & 31, h = l >> 5;
    const int qcloud = task;
    const float* qRaw = (qcloud < 2 ? src : tgt)
                        + (size_t)3 * (size_t)((qcloud & 1) * N);
    const int qloc = qc * 256 + w * 64 + col;
    float qa[3], qb[3];
    #pragma unroll
    for (int d = 0; d < 3; ++d) {
        qa[d] = qRaw[3*qloc + d];
        qb[d] = qRaw[3*(qloc+32) + d];
    }
    const float qqa = qa[0]*qa[0] + qa[1]*qa[1] + qa[2]*qa[2];
    const float qqb = qb[0]*qb[0] + qb[1]*qb[1] + qb[2]*qb[2];

    unsigned short B0[8], B1[8];
    #pragma unroll
    for (int d = 0; d < 3; ++d) {
        const unsigned short ha = bf16h(qa[d]);
        const unsigned short hb = bf16h(qb[d]);
        B0[d] = ha; B1[d] = hb;
        B0[4+d] = (h == 0) ? bf16h(qa[d] - bf16v(ha)) : (unsigned short)0;
        B1[4+d] = (h == 0) ? bf16h(qb[d] - bf16v(hb)) : (unsigned short)0;
    }
    B0[3] = B0[7] = (h == 0) ? (unsigned short)0x3F80 : (unsigned short)0;
    B1[3] = B1[7] = B0[3];
    const short8 b0 = *(const short8*)B0;
    const short8 b1 = *(const short8*)B1;

    __syncthreads();

    // ---- 3) MFMA loop over 32 tiles ----
    const int lbase = h * LDS_HALF + col * 16 + (col >> 3) * 16;
    float best0 = 3.4e38f, best1 = 3.4e38f;
    const f32x16 zero = {};
    #pragma unroll 4
    for (int i = 0; i < 32; ++i) {
        const short8 a = *(const short8*)(Alds + i * LDS_TILE + lbase);
        f32x16 d0 = __builtin_amdgcn_mfma_f32_32x32x16_bf16(a, b0, zero, 0, 0, 0);
        f32x16 d1 = __builtin_amdgcn_mfma_f32_32x32x16_bf16(a, b1, zero, 0, 0, 0);
        best0 = fminf(fminf(d0[0],  d0[1]),  best0);
        best0 = fminf(fminf(d0[2],  d0[3]),  best0);
        best0 = fminf(fminf(d0[4],  d0[5]),  best0);
        best0 = fminf(fminf(d0[6],  d0[7]),  best0);
        best0 = fminf(fminf(d0[8],  d0[9]),  best0);
        best0 = fminf(fminf(d0[10], d0[11]), best0);
        best0 = fminf(fminf(d0[12], d0[13]), best0);
        best0 = fminf(fminf(d0[14], d0[15]), best0);
        best1 = fminf(fminf(d1[0],  d1[1]),  best1);
        best1 = fminf(fminf(d1[2],  d1[3]),  best1);
        best1 = fminf(fminf(d1[4],  d1[5]),  best1);
        best1 = fminf(fminf(d1[6],  d1[7]),  best1);
        best1 = fminf(fminf(d1[8],  d1[9]),  best1);
        best1 = fminf(fminf(d1[10], d1[11]), best1);
        best1 = fminf(fminf(d1[12], d1[13]), best1);
        best1 = fminf(fminf(d1[14], d1[15]), best1);
    }

    // ---- 4) merge + atomicMin ----
    best0 = fminf(best0, __shfl_xor(best0, 32));
    best1 = fminf(best1, __shfl_xor(best1, 32));
    const int qbase = task * N + qc * 256 + w * 64;
    if (l < 32) {
        atomicMin(&d2min[qbase + l],
                  __float_as_uint(fmaxf(best0 + qqa, 0.0f)));
        atomicMin(&d2min[qbase + l + 32],
                  __float_as_uint(fmaxf(best1 + qqb, 0.0f)));
    }

    // ---- 5) last-block deterministic reduce ----
    __shared__ int isLast;
    __shared__ double ws0[4], ws1[4];
    __syncthreads();
    if (t == 0) {
        __threadfence();
        isLast = (atomicAdd(counter, 1u) == gridDim.x - 1) ? 1 : 0;
    }
    __syncthreads();
    if (!isLast) return;
    __threadfence();

    const int QT = 4 * N, twoN = 2 * N;
    double s0 = 0.0, s1 = 0.0;
    for (int i = t; i < QT; i += 256) {
        const float d2 = __uint_as_float(d2min[i]);
        const float f = sqrtf(1.0f + d2) + sqrtf(d2);
        if (i < twoN) s0 += (double)f; else s1 += (double)f;
    }
    for (int o = 32; o > 0; o >>= 1) {
        s0 += __shfl_down(s0, o);
        s1 += __shfl_down(s1, o);
    }
    if ((t & 63) == 0) { ws0[t >> 6] = s0; ws1[t >> 6] = s1; }
    __syncthreads();
    if (t == 0) {
        const double t0 = ws0[0] + ws0[1] + ws0[2] + ws0[3];
        const double t1 = ws1[0] + ws1[1] + ws1[2] + ws1[3];
        const double inv = 1.0 / (double)twoN;
        double l0 = (t0 * inv - 1.0) * 0.5;
        double l1 = (t1 * inv - 1.0) * 0.5;
        l0 = l0 < 0.0 ? 0.0 : (l0 > 1.0 ? 1.0 : l0);
        l1 = l1 < 0.0 ? 0.0 : (l1 > 1.0 ? 1.0 : l1);
        out[0] = (float)(0.5 * (l0 + l1));
    }
}

extern "C" void kernel_launch(void* const* d_in, const int* in_sizes, int n_in,
                              void* d_out, int out_size, void* d_ws, size_t ws_size,
                              hipStream_t stream) {
    const float* src = (const float*)d_in[0];
    const float* tgt = (const float*)d_in[1];
    float* out = (float*)d_out;

    const int twoN = in_sizes[0] / 3;    // 16384 points per input
    const int N    = twoN / 2;           // 8192
    const int QT   = 4 * N;              // 32768 total queries

    unsigned* counter = (unsigned*)d_ws;
    unsigned* d2min   = (unsigned*)((char*)d_ws + 64);

    hipMemsetAsync(d_ws, 0, 64, stream);                                   // counter
    hipMemsetAsync(d2min, 0x7f, (size_t)QT * sizeof(unsigned), stream);    // +3.39e38

    const int blocks = 4 * (N >> 8) * (N / PPB);   // 1024
    fused_kernel<<<blocks, 256, 0, stream>>>(src, tgt, d2min, counter, out, N);
}

// Round 13
// 37.040 us; speedup vs baseline: 2.1606x; 2.1606x over previous
//
#include <hip/hip_runtime.h>

// ============================================================================
// PGALoss, analytically reduced:
//   per-point loss = sqrt(1 + d^2) + d,  d = NN distance
//   out = 0.5 * sum_dir clip((mean loss - 1)/2, 0, 1)
// d^2 = min_p(||p||^2 - 2 q.p) + ||q||^2   via bf16 hi/lo-split MFMA (R10)
//
// R13: R10 verbatim EXCEPT the contested global atomicMin merge (the
// suspected ~25-30us drain: 262K device-scope RMWs onto 128KB, gating
// dispatch completion) is replaced by plain coalesced stores into
// partial[PS][QT]; reduce min-folds the PS=8 slots inline. 3 kernels,
// 0 memsets, only trivial atomics remain (2-word f64 acc + counter).
// ============================================================================

typedef short short8 __attribute__((ext_vector_type(8)));
typedef float f32x16 __attribute__((ext_vector_type(16)));

#define TPB 256
#define PS  8     // point-split: blocks = 4 * (N/256) * PS = 1024

// ws: [0,4) counter | [16,32) acc[2] | [64) PParr[QT] f32
//     | +QT*4: partial[PS][QT] f32 | +QT*36: Abuf[QT*16 ushort] | Bbuf[...]

__device__ __forceinline__ unsigned short bf16h(float f) {
    unsigned u = __float_as_uint(f);
    return (unsigned short)((u + 0x7fffu + ((u >> 16) & 1u)) >> 16);
}
__device__ __forceinline__ float bf16v(unsigned short h) {
    return __uint_as_float((unsigned)h << 16);
}

__global__ __launch_bounds__(256)
void prep_kernel(const float* __restrict__ src, const float* __restrict__ tgt,
                 unsigned short* __restrict__ Abuf, unsigned short* __restrict__ Bbuf,
                 float* __restrict__ PParr, double* __restrict__ acc,
                 unsigned* __restrict__ counter, int N) {
    const int g = blockIdx.x * 256 + threadIdx.x;    // [0, 4N)
    if (g < 2) acc[g] = 0.0;
    if (g == 2) *counter = 0u;
    const int QT = 4 * N;
    if (g >= QT) return;

    const int twoN = 2 * N;
    const float* in = (g >= twoN) ? tgt : src;
    const int i = (g >= twoN) ? (g - twoN) : g;
    const float x = in[3*i], y = in[3*i+1], z = in[3*i+2];
    const float pp = x*x + y*y + z*z;
    PParr[g] = pp;

    alignas(16) unsigned short A16[16];
    alignas(16) unsigned short B16[16];
    const float q[3] = {x, y, z};
    #pragma unroll
    for (int d = 0; d < 3; ++d) {
        unsigned short qh = bf16h(q[d]);
        unsigned short ql = bf16h(q[d] - bf16v(qh));
        B16[d] = qh; B16[4+d] = ql; B16[8+d] = qh;
        const float t = -2.0f * q[d];
        unsigned short th = bf16h(t);
        unsigned short tl = bf16h(t - bf16v(th));
        A16[d] = th; A16[4+d] = th; A16[8+d] = tl;
    }
    const unsigned short pph = bf16h(pp);
    const unsigned short ppl = bf16h(pp - bf16v(pph));
    A16[3] = pph; A16[7] = ppl; A16[11] = 0;
    B16[3] = 0x3F80u; B16[7] = 0x3F80u; B16[11] = 0;  // bf16 1.0
    #pragma unroll
    for (int s = 12; s < 16; ++s) { A16[s] = 0; B16[s] = 0; }

    // fragment packet: tile = g>>5 (1024B), row r = g&31:
    //   k 0..7 at tile*512 + r*8 (ushort units), k 8..15 at +256
    const size_t tile = (size_t)(g >> 5), r = (size_t)(g & 31);
    unsigned short* Ad = Abuf + tile * 512 + r * 8;
    unsigned short* Bd = Bbuf + tile * 512 + r * 8;
    *(short8*)(Ad)       = *(const short8*)(A16);
    *(short8*)(Ad + 256) = *(const short8*)(A16 + 8);
    *(short8*)(Bd)       = *(const short8*)(B16);
    *(short8*)(Bd + 256) = *(const short8*)(B16 + 8);
}

__global__ __launch_bounds__(TPB)
void nn_kernel(const unsigned short* __restrict__ Abuf,
               const unsigned short* __restrict__ Bbuf,
               const float* __restrict__ PParr,
               float* __restrict__ partial, int N) {
    const int tid = threadIdx.x;
    const int l = tid & 63;              // lane
    const int w = tid >> 6;              // wave 0..3
    const int nqc  = N >> 8;             // query chunks (256 q per block)
    const int bpt  = nqc * PS;
    const int task = blockIdx.x / bpt;   // 0..3 = s0,s1,t0,t1
    const int rem  = blockIdx.x % bpt;
    const int qc = rem / PS, pc = rem % PS;

    const size_t laneoff = (size_t)((l >> 5) * 256 + (l & 31) * 8);

    const int qbase = task * N + qc * 256 + w * 64;   // 64 queries per wave
    const size_t qt0 = (size_t)(qbase >> 5);
    const short8 b0 = *(const short8*)(Bbuf + qt0 * 512 + laneoff);
    const short8 b1 = *(const short8*)(Bbuf + (qt0 + 1) * 512 + laneoff);

    const int ppb    = N / PS;                        // 1024 points per block
    const int pbase  = (task ^ 2) * N + pc * ppb;
    const int ntiles = ppb >> 5;                      // 32
    const unsigned short* ap = Abuf + (size_t)(pbase >> 5) * 512 + laneoff;

    float best0 = 3.4e38f, best1 = 3.4e38f;
    const f32x16 z = {};
    #pragma unroll 2
    for (int i = 0; i < ntiles; ++i) {
        const short8 a = *(const short8*)ap;          // A-frag: 32 points x K16
        ap += 512;
        f32x16 d0 = __builtin_amdgcn_mfma_f32_32x32x16_bf16(a, b0, z, 0, 0, 0);
        f32x16 d1 = __builtin_amdgcn_mfma_f32_32x32x16_bf16(a, b1, z, 0, 0, 0);
        best0 = fminf(fminf(d0[0],  d0[1]),  best0);  // v_min3_f32 x8
        best0 = fminf(fminf(d0[2],  d0[3]),  best0);
        best0 = fminf(fminf(d0[4],  d0[5]),  best0);
        best0 = fminf(fminf(d0[6],  d0[7]),  best0);
        best0 = fminf(fminf(d0[8],  d0[9]),  best0);
        best0 = fminf(fminf(d0[10], d0[11]), best0);
        best0 = fminf(fminf(d0[12], d0[13]), best0);
        best0 = fminf(fminf(d0[14], d0[15]), best0);
        best1 = fminf(fminf(d1[0],  d1[1]),  best1);
        best1 = fminf(fminf(d1[2],  d1[3]),  best1);
        best1 = fminf(fminf(d1[4],  d1[5]),  best1);
        best1 = fminf(fminf(d1[6],  d1[7]),  best1);
        best1 = fminf(fminf(d1[8],  d1[9]),  best1);
        best1 = fminf(fminf(d1[10], d1[11]), best1);
        best1 = fminf(fminf(d1[12], d1[13]), best1);
        best1 = fminf(fminf(d1[14], d1[15]), best1);
    }
    best0 = fminf(best0, __shfl_xor(best0, 32));
    best1 = fminf(best1, __shfl_xor(best1, 32));
    if (l < 32) {
        const int q0 = qbase + l;
        // clamp(min+qq) commutes with the later min-fold (max(.,0) monotone)
        const float e0 = fmaxf(best0 + PParr[q0], 0.0f);
        const float e1 = fmaxf(best1 + PParr[q0 + 32], 0.0f);
        float* dst = partial + (size_t)pc * (size_t)(4 * N);
        dst[q0]      = e0;     // plain coalesced stores, unique slot per block
        dst[q0 + 32] = e1;
    }
}

__global__ __launch_bounds__(256)
void reduce_kernel(const float* __restrict__ partial, double* __restrict__ acc,
                   unsigned* __restrict__ counter, float* __restrict__ out, int N) {
    const int gq = blockIdx.x * 256 + threadIdx.x;   // [0, 4N)
    const int QT = 4 * N;
    float d2 = partial[gq];
    #pragma unroll
    for (int ps = 1; ps < PS; ++ps)
        d2 = fminf(d2, partial[(size_t)ps * QT + gq]);
    float f = sqrtf(1.0f + d2) + sqrtf(d2);
    for (int o = 32; o > 0; o >>= 1) f += __shfl_down(f, o);
    const int dir = gq / (2 * N);                    // wave-uniform
    if ((threadIdx.x & 63) == 0) atomicAdd(&acc[dir], (double)f);
    __syncthreads();
    if (threadIdx.x == 0) {
        __threadfence();
        const unsigned old = atomicAdd(counter, 1u);
        if (old == gridDim.x - 1) {                  // last block finalizes
            const double s0 = atomicAdd(&acc[0], 0.0);
            const double s1 = atomicAdd(&acc[1], 0.0);
            const double inv = 1.0 / (double)(2 * N);
            double l0 = (s0 * inv - 1.0) * 0.5;
            double l1 = (s1 * inv - 1.0) * 0.5;
            l0 = l0 < 0.0 ? 0.0 : (l0 > 1.0 ? 1.0 : l0);
            l1 = l1 < 0.0 ? 0.0 : (l1 > 1.0 ? 1.0 : l1);
            out[0] = (float)(0.5 * (l0 + l1));
        }
    }
}

extern "C" void kernel_launch(void* const* d_in, const int* in_sizes, int n_in,
                              void* d_out, int out_size, void* d_ws, size_t ws_size,
                              hipStream_t stream) {
    const float* src = (const float*)d_in[0];
    const float* tgt = (const float*)d_in[1];
    float* out = (float*)d_out;

    const int twoN = in_sizes[0] / 3;    // 16384 points per input
    const int N    = twoN / 2;           // 8192
    const int QT   = 4 * N;              // 32768

    unsigned* counter    = (unsigned*)d_ws;
    double* acc          = (double*)((char*)d_ws + 16);
    float* PParr         = (float*)((char*)d_ws + 64);
    float* partial       = (float*)((char*)d_ws + 64 + (size_t)QT * 4);
    unsigned short* Abuf = (unsigned short*)((char*)d_ws + 64 + (size_t)QT * 4
                                             + (size_t)PS * QT * 4);
    unsigned short* Bbuf = Abuf + (size_t)QT * 16;   // QT*32 bytes each

    prep_kernel<<<(QT + 255) / 256, 256, 0, stream>>>(
        src, tgt, Abuf, Bbuf, PParr, acc, counter, N);

    const int blocks = 4 * (N >> 8) * PS;   // 1024
    nn_kernel<<<blocks, TPB, 0, stream>>>(Abuf, Bbuf, PParr, partial, N);

    reduce_kernel<<<QT / 256, 256, 0, stream>>>(partial, acc, counter, out, N);
}

// Round 14
// 26.212 us; speedup vs baseline: 3.0532x; 1.4131x over previous
//
#include <hip/hip_runtime.h>

// ============================================================================
// PGALoss, analytically reduced:
//   per-point loss = sqrt(1 + d^2) + d,  d = NN distance
//   out = 0.5 * sum_dir clip((mean loss - 1)/2, 0, 1)
// d^2 = min_p(||p||^2 - 2 q.p) + ||q||^2   via bf16 hi/lo-split MFMA (R10)
//
// R14: TWO nodes total (suspected ~8-9us/node graph overhead is the floor).
//  node1 fused nn: per-block LDS prep of its 1024-point A-chunk (R12,
//    proven) + in-register B-frags + 32-tile MFMA loop + plain partial
//    stores (R13, proven). NO atomics, NO fences in this kernel; block 0
//    zeroes acc/counter for node2.
//  node2 reduce: min-fold PS=8 partials + f64 sum + last-block finalize
//    (R13 verbatim, proven cheap).
// ============================================================================

typedef short short8 __attribute__((ext_vector_type(8)));
typedef float f32x16 __attribute__((ext_vector_type(16)));

#define PPB      1024            // points per block
#define PS       8               // point chunks (N/PPB)
#define LDS_HALF 576             // 32 rows * 16B + 4 * 16B pad
#define LDS_TILE 1152            // two k-halves

// ws: [0,4) counter | [16,32) acc[2] | [64,...) partial[PS][QT] f32 (1 MB)

__device__ __forceinline__ unsigned short bf16h(float f) {
    unsigned u = __float_as_uint(f);
    return (unsigned short)((u + 0x7fffu + ((u >> 16) & 1u)) >> 16);
}
__device__ __forceinline__ float bf16v(unsigned short h) {
    return __uint_as_float((unsigned)h << 16);
}

__global__ __launch_bounds__(256, 4)
void nn_kernel(const float* __restrict__ src, const float* __restrict__ tgt,
               float* __restrict__ partial, double* __restrict__ acc,
               unsigned* __restrict__ counter, int N) {
    __shared__ __align__(16) unsigned char Alds[32 * LDS_TILE];  // 36 KB

    const int t = threadIdx.x;
    if (blockIdx.x == 0) {                   // init for node2 (visible at node
        if (t < 2) acc[t] = 0.0;             // boundary; no fence needed)
        if (t == 2) *counter = 0u;
    }

    const int l   = t & 63, w = t >> 6;
    const int nqc = N >> 8;                  // 32 query chunks (256 q each)
    const int bpt = nqc * PS;                // 256 blocks per task
    const int task = blockIdx.x / bpt;       // 0..3 = s0,s1,t0,t1
    const int rem  = blockIdx.x % bpt;
    const int qc = rem / PS, pc = rem % PS;

    // ---- A-prep: 1024 points of cloud (task^2), chunk pc -> LDS ----
    const int pcloud = task ^ 2;
    const float* pRaw = (pcloud < 2 ? src : tgt)
                        + (size_t)3 * ((size_t)(pcloud & 1) * N + (size_t)pc * PPB);
    #pragma unroll
    for (int k = 0; k < 4; ++k) {
        const int j = t + k * 256;           // local point index 0..1023
        const float x = pRaw[3*j], y = pRaw[3*j+1], z = pRaw[3*j+2];
        const float pp = x*x + y*y + z*z;
        unsigned short A16[16];
        const float p3[3] = {x, y, z};
        #pragma unroll
        for (int d = 0; d < 3; ++d) {
            const float m2 = -2.0f * p3[d];
            const unsigned short th = bf16h(m2);
            A16[d] = th; A16[4+d] = th; A16[8+d] = bf16h(m2 - bf16v(th));
        }
        const unsigned short pph = bf16h(pp);
        A16[3] = pph; A16[7] = bf16h(pp - bf16v(pph)); A16[11] = 0;
        A16[12] = A16[13] = A16[14] = A16[15] = 0;
        const int tile = j >> 5, r = j & 31;
        unsigned char* base = Alds + tile * LDS_TILE + r * 16 + (r >> 3) * 16;
        *(short8*)(base)            = *(const short8*)(A16);      // k 0..7
        *(short8*)(base + LDS_HALF) = *(const short8*)(A16 + 8);  // k 8..15
    }

    // ---- B-fragments in registers (lane owns cols l&31 of 2 B-tiles) ----
    const int col = l & 31, h = l >> 5;
    const float* qRaw = (task < 2 ? src : tgt)
                        + (size_t)3 * (size_t)((task & 1) * N);
    const int qloc = qc * 256 + w * 64 + col;
    float qa[3], qb[3];
    #pragma unroll
    for (int d = 0; d < 3; ++d) {
        qa[d] = qRaw[3*qloc + d];
        qb[d] = qRaw[3*(qloc+32) + d];
    }
    const float qqa = qa[0]*qa[0] + qa[1]*qa[1] + qa[2]*qa[2];
    const float qqb = qb[0]*qb[0] + qb[1]*qb[1] + qb[2]*qb[2];

    unsigned short B0[8], B1[8];
    #pragma unroll
    for (int d = 0; d < 3; ++d) {
        const unsigned short ha = bf16h(qa[d]);
        const unsigned short hb = bf16h(qb[d]);
        B0[d] = ha; B1[d] = hb;
        B0[4+d] = (h == 0) ? bf16h(qa[d] - bf16v(ha)) : (unsigned short)0;
        B1[4+d] = (h == 0) ? bf16h(qb[d] - bf16v(hb)) : (unsigned short)0;
    }
    B0[3] = B0[7] = (h == 0) ? (unsigned short)0x3F80 : (unsigned short)0;
    B1[3] = B1[7] = B0[3];
    const short8 b0 = *(const short8*)B0;
    const short8 b1 = *(const short8*)B1;

    __syncthreads();

    // ---- MFMA loop over 32 tiles ----
    const int lbase = h * LDS_HALF + col * 16 + (col >> 3) * 16;
    float best0 = 3.4e38f, best1 = 3.4e38f;
    const f32x16 zero = {};
    #pragma unroll 4
    for (int i = 0; i < 32; ++i) {
        const short8 a = *(const short8*)(Alds + i * LDS_TILE + lbase);
        f32x16 d0 = __builtin_amdgcn_mfma_f32_32x32x16_bf16(a, b0, zero, 0, 0, 0);
        f32x16 d1 = __builtin_amdgcn_mfma_f32_32x32x16_bf16(a, b1, zero, 0, 0, 0);
        best0 = fminf(fminf(d0[0],  d0[1]),  best0);
        best0 = fminf(fminf(d0[2],  d0[3]),  best0);
        best0 = fminf(fminf(d0[4],  d0[5]),  best0);
        best0 = fminf(fminf(d0[6],  d0[7]),  best0);
        best0 = fminf(fminf(d0[8],  d0[9]),  best0);
        best0 = fminf(fminf(d0[10], d0[11]), best0);
        best0 = fminf(fminf(d0[12], d0[13]), best0);
        best0 = fminf(fminf(d0[14], d0[15]), best0);
        best1 = fminf(fminf(d1[0],  d1[1]),  best1);
        best1 = fminf(fminf(d1[2],  d1[3]),  best1);
        best1 = fminf(fminf(d1[4],  d1[5]),  best1);
        best1 = fminf(fminf(d1[6],  d1[7]),  best1);
        best1 = fminf(fminf(d1[8],  d1[9]),  best1);
        best1 = fminf(fminf(d1[10], d1[11]), best1);
        best1 = fminf(fminf(d1[12], d1[13]), best1);
        best1 = fminf(fminf(d1[14], d1[15]), best1);
    }

    // ---- merge + plain partial stores (unique slot per block) ----
    best0 = fminf(best0, __shfl_xor(best0, 32));
    best1 = fminf(best1, __shfl_xor(best1, 32));
    if (l < 32) {
        const int q0 = task * N + qc * 256 + w * 64 + l;
        float* dst = partial + (size_t)pc * (size_t)(4 * N);
        dst[q0]      = fmaxf(best0 + qqa, 0.0f);   // clamp commutes with min
        dst[q0 + 32] = fmaxf(best1 + qqb, 0.0f);
    }
}

__global__ __launch_bounds__(256)
void reduce_kernel(const float* __restrict__ partial, double* __restrict__ acc,
                   unsigned* __restrict__ counter, float* __restrict__ out, int N) {
    const int gq = blockIdx.x * 256 + threadIdx.x;   // [0, 4N)
    const int QT = 4 * N;
    float d2 = partial[gq];
    #pragma unroll
    for (int ps = 1; ps < PS; ++ps)
        d2 = fminf(d2, partial[(size_t)ps * QT + gq]);
    float f = sqrtf(1.0f + d2) + sqrtf(d2);
    for (int o = 32; o > 0; o >>= 1) f += __shfl_down(f, o);
    const int dir = gq / (2 * N);                    // wave-uniform
    if ((threadIdx.x & 63) == 0) atomicAdd(&acc[dir], (double)f);
    __syncthreads();
    if (threadIdx.x == 0) {
        __threadfence();
        const unsigned old = atomicAdd(counter, 1u);
        if (old == gridDim.x - 1) {                  // last block finalizes
            const double s0 = atomicAdd(&acc[0], 0.0);
            const double s1 = atomicAdd(&acc[1], 0.0);
            const double inv = 1.0 / (double)(2 * N);
            double l0 = (s0 * inv - 1.0) * 0.5;
            double l1 = (s1 * inv - 1.0) * 0.5;
            l0 = l0 < 0.0 ? 0.0 : (l0 > 1.0 ? 1.0 : l0);
            l1 = l1 < 0.0 ? 0.0 : (l1 > 1.0 ? 1.0 : l1);
            out[0] = (float)(0.5 * (l0 + l1));
        }
    }
}

extern "C" void kernel_launch(void* const* d_in, const int* in_sizes, int n_in,
                              void* d_out, int out_size, void* d_ws, size_t ws_size,
                              hipStream_t stream) {
    const float* src = (const float*)d_in[0];
    const float* tgt = (const float*)d_in[1];
    float* out = (float*)d_out;

    const int twoN = in_sizes[0] / 3;    // 16384 points per input
    const int N    = twoN / 2;           // 8192
    const int QT   = 4 * N;              // 32768

    unsigned* counter = (unsigned*)d_ws;
    double* acc       = (double*)((char*)d_ws + 16);
    float* partial    = (float*)((char*)d_ws + 64);

    const int blocks = 4 * (N >> 8) * (N / PPB);   // 1024
    nn_kernel<<<blocks, 256, 0, stream>>>(src, tgt, partial, acc, counter, N);

    reduce_kernel<<<QT / 256, 256, 0, stream>>>(partial, acc, counter, out, N);
}

// Round 16
// 24.783 us; speedup vs baseline: 3.2293x; 1.0577x over previous
//
#include <hip/hip_runtime.h>

// ============================================================================
// PGALoss, analytically reduced:
//   per-point loss = sqrt(1 + d^2) + d,  d = NN distance
//   out = 0.5 * sum_dir clip((mean loss - 1)/2, 0, 1)
// d^2 = min_p(||p||^2 - 2 q.p) + ||q||^2   via bf16 hi/lo-split MFMA (R10)
//
// R16: R15 with the race fixed. R15's accP was a PLAIN store read by a
// block on another XCD (per-XCD L2s not coherent) -> stale partials.
// Now EVERY cross-block hop is a device-scope atomic:
//   d2min: atomicMin write / atomicOr read
//   accP : atomicExch write / atomicOr read   (returns consumed -> ordered)
//   chunkCnt/finalCnt: atomicAdd
// 1 memset node (0x7f = counters' known init AND d2min's +inf) + 1 kernel.
// ============================================================================

typedef short short8 __attribute__((ext_vector_type(8)));
typedef float f32x16 __attribute__((ext_vector_type(16)));

#define PPB      1024            // points per block
#define PS       8               // point chunks (N/PPB)
#define LDS_HALF 576             // 32 rows * 16B + 4 * 16B pad
#define LDS_TILE 1152            // two k-halves

// ws layout (memset 0x7f covers [0, 2048 + 4*QT)):
//   [0,512)     chunkCnt[128] u32   (init 0x7f7f7f7f)
//   [512,516)   finalCnt u32        (init 0x7f7f7f7f)
//   [1024,1536) accP[128] u32       (atomicExch-written float bits)
//   [2048,...)  d2min[QT] u32       (init 0x7f7f7f7f = +huge)

__device__ __forceinline__ unsigned short bf16h(float f) {
    unsigned u = __float_as_uint(f);
    return (unsigned short)((u + 0x7fffu + ((u >> 16) & 1u)) >> 16);
}
__device__ __forceinline__ float bf16v(unsigned short h) {
    return __uint_as_float((unsigned)h << 16);
}

__global__ __launch_bounds__(256, 4)
void fused_kernel(const float* __restrict__ src, const float* __restrict__ tgt,
                  unsigned* __restrict__ chunkCnt, unsigned* __restrict__ finalCnt,
                  unsigned* __restrict__ accP, unsigned* __restrict__ d2min,
                  float* __restrict__ out, int N) {
    __shared__ __align__(16) unsigned char Alds[32 * LDS_TILE];  // 36 KB

    const int t   = threadIdx.x;
    const int l   = t & 63, w = t >> 6;
    const int nqc = N >> 8;                  // 32 query chunks (256 q each)
    const int bpt = nqc * PS;                // 256 blocks per task
    const int task = blockIdx.x / bpt;       // 0..3 = s0,s1,t0,t1
    const int rem  = blockIdx.x % bpt;
    const int qc = rem / PS, pc = rem % PS;

    // ---- A-prep: 1024 points of cloud (task^2), chunk pc -> LDS ----
    const int pcloud = task ^ 2;
    const float* pRaw = (pcloud < 2 ? src : tgt)
                        + (size_t)3 * ((size_t)(pcloud & 1) * N + (size_t)pc * PPB);
    #pragma unroll
    for (int k = 0; k < 4; ++k) {
        const int j = t + k * 256;
        const float x = pRaw[3*j], y = pRaw[3*j+1], z = pRaw[3*j+2];
        const float pp = x*x + y*y + z*z;
        unsigned short A16[16];
        const float p3[3] = {x, y, z};
        #pragma unroll
        for (int d = 0; d < 3; ++d) {
            const float m2 = -2.0f * p3[d];
            const unsigned short th = bf16h(m2);
            A16[d] = th; A16[4+d] = th; A16[8+d] = bf16h(m2 - bf16v(th));
        }
        const unsigned short pph = bf16h(pp);
        A16[3] = pph; A16[7] = bf16h(pp - bf16v(pph)); A16[11] = 0;
        A16[12] = A16[13] = A16[14] = A16[15] = 0;
        const int tile = j >> 5, r = j & 31;
        unsigned char* base = Alds + tile * LDS_TILE + r * 16 + (r >> 3) * 16;
        *(short8*)(base)            = *(const short8*)(A16);
        *(short8*)(base + LDS_HALF) = *(const short8*)(A16 + 8);
    }

    // ---- B-fragments in registers ----
    const int col = l & 31, h = l >> 5;
    const float* qRaw = (task < 2 ? src : tgt)
                        + (size_t)3 * (size_t)((task & 1) * N);
    const int qloc = qc * 256 + w * 64 + col;
    float qa[3], qb[3];
    #pragma unroll
    for (int d = 0; d < 3; ++d) {
        qa[d] = qRaw[3*qloc + d];
        qb[d] = qRaw[3*(qloc+32) + d];
    }
    const float qqa = qa[0]*qa[0] + qa[1]*qa[1] + qa[2]*qa[2];
    const float qqb = qb[0]*qb[0] + qb[1]*qb[1] + qb[2]*qb[2];

    unsigned short B0[8], B1[8];
    #pragma unroll
    for (int d = 0; d < 3; ++d) {
        const unsigned short ha = bf16h(qa[d]);
        const unsigned short hb = bf16h(qb[d]);
        B0[d] = ha; B1[d] = hb;
        B0[4+d] = (h == 0) ? bf16h(qa[d] - bf16v(ha)) : (unsigned short)0;
        B1[4+d] = (h == 0) ? bf16h(qb[d] - bf16v(hb)) : (unsigned short)0;
    }
    B0[3] = B0[7] = (h == 0) ? (unsigned short)0x3F80 : (unsigned short)0;
    B1[3] = B1[7] = B0[3];
    const short8 b0 = *(const short8*)B0;
    const short8 b1 = *(const short8*)B1;

    __syncthreads();

    // ---- MFMA loop over 32 tiles ----
    const int lbase = h * LDS_HALF + col * 16 + (col >> 3) * 16;
    float best0 = 3.4e38f, best1 = 3.4e38f;
    const f32x16 zero = {};
    #pragma unroll 4
    for (int i = 0; i < 32; ++i) {
        const short8 a = *(const short8*)(Alds + i * LDS_TILE + lbase);
        f32x16 d0 = __builtin_amdgcn_mfma_f32_32x32x16_bf16(a, b0, zero, 0, 0, 0);
        f32x16 d1 = __builtin_amdgcn_mfma_f32_32x32x16_bf16(a, b1, zero, 0, 0, 0);
        best0 = fminf(fminf(d0[0],  d0[1]),  best0);
        best0 = fminf(fminf(d0[2],  d0[3]),  best0);
        best0 = fminf(fminf(d0[4],  d0[5]),  best0);
        best0 = fminf(fminf(d0[6],  d0[7]),  best0);
        best0 = fminf(fminf(d0[8],  d0[9]),  best0);
        best0 = fminf(fminf(d0[10], d0[11]), best0);
        best0 = fminf(fminf(d0[12], d0[13]), best0);
        best0 = fminf(fminf(d0[14], d0[15]), best0);
        best1 = fminf(fminf(d1[0],  d1[1]),  best1);
        best1 = fminf(fminf(d1[2],  d1[3]),  best1);
        best1 = fminf(fminf(d1[4],  d1[5]),  best1);
        best1 = fminf(fminf(d1[6],  d1[7]),  best1);
        best1 = fminf(fminf(d1[8],  d1[9]),  best1);
        best1 = fminf(fminf(d1[10], d1[11]), best1);
        best1 = fminf(fminf(d1[12], d1[13]), best1);
        best1 = fminf(fminf(d1[14], d1[15]), best1);
    }

    // ---- merge + atomicMin (returns consumed -> complete before counter) ----
    best0 = fminf(best0, __shfl_xor(best0, 32));
    best1 = fminf(best1, __shfl_xor(best1, 32));
    const int qbase = task * N + qc * 256;
    if (l < 32) {
        const int q0 = qbase + w * 64 + l;
        unsigned o0 = atomicMin(&d2min[q0],
                                __float_as_uint(fmaxf(best0 + qqa, 0.0f)));
        unsigned o1 = atomicMin(&d2min[q0 + 32],
                                __float_as_uint(fmaxf(best1 + qqb, 0.0f)));
        asm volatile("" :: "v"(o0), "v"(o1));   // forces vmcnt drain
    }

    // ---- chunk-last detection ----
    __shared__ int lastChunk;
    __syncthreads();
    if (t == 0)
        lastChunk = (atomicAdd(&chunkCnt[task * nqc + qc], 1u)
                     == 0x7f7f7f7fu + (unsigned)PS - 1u);
    __syncthreads();
    if (!lastChunk) return;

    // ---- chunk finalize: 256 queries, atomic-coherent reads ----
    const float d2 = __uint_as_float(atomicOr(&d2min[qbase + t], 0u));
    double fv = (double)(sqrtf(1.0f + d2) + sqrtf(d2));
    #pragma unroll
    for (int o = 32; o > 0; o >>= 1) fv += __shfl_down(fv, o);
    __shared__ double wsum[4];
    __shared__ int lastFinal;
    if (l == 0) wsum[w] = fv;
    __syncthreads();
    if (t == 0) {
        const float csum = (float)(wsum[0] + wsum[1] + wsum[2] + wsum[3]);
        unsigned oldA = atomicExch(&accP[task * nqc + qc], __float_as_uint(csum));
        asm volatile("" :: "v"(oldA));          // exch complete at coherence
        lastFinal = (atomicAdd(finalCnt, 1u)
                     == 0x7f7f7f7fu + (unsigned)(4 * nqc) - 1u);
    }
    __syncthreads();
    if (!lastFinal) return;

    // ---- global finalize (exactly one block) ----
    __shared__ float pvals[128];
    const int ncid = 4 * nqc;                    // 128
    if (t < ncid) pvals[t] = __uint_as_float(atomicOr(&accP[t], 0u));
    __syncthreads();
    if (t == 0) {
        double s0 = 0.0, s1 = 0.0;
        for (int i = 0; i < ncid / 2; ++i)        s0 += (double)pvals[i];
        for (int i = ncid / 2; i < ncid; ++i)     s1 += (double)pvals[i];
        const double inv = 1.0 / (double)(2 * N);
        double l0 = (s0 * inv - 1.0) * 0.5;
        double l1 = (s1 * inv - 1.0) * 0.5;
        l0 = l0 < 0.0 ? 0.0 : (l0 > 1.0 ? 1.0 : l0);
        l1 = l1 < 0.0 ? 0.0 : (l1 > 1.0 ? 1.0 : l1);
        out[0] = (float)(0.5 * (l0 + l1));
    }
}

extern "C" void kernel_launch(void* const* d_in, const int* in_sizes, int n_in,
                              void* d_out, int out_size, void* d_ws, size_t ws_size,
                              hipStream_t stream) {
    const float* src = (const float*)d_in[0];
    const float* tgt = (const float*)d_in[1];
    float* out = (float*)d_out;

    const int twoN = in_sizes[0] / 3;    // 16384 points per input
    const int N    = twoN / 2;           // 8192
    const int QT   = 4 * N;              // 32768

    unsigned* chunkCnt = (unsigned*)d_ws;
    unsigned* finalCnt = (unsigned*)((char*)d_ws + 512);
    unsigned* accP     = (unsigned*)((char*)d_ws + 1024);
    unsigned* d2min    = (unsigned*)((char*)d_ws + 2048);

    // one memset node: counters AND d2min (+inf as uint) all 0x7f7f7f7f
    hipMemsetAsync(d_ws, 0x7f, 2048 + (size_t)QT * sizeof(unsigned), stream);

    const int blocks = 4 * (N >> 8) * PS;   // 1024
    fused_kernel<<<blocks, 256, 0, stream>>>(src, tgt, chunkCnt, finalCnt,
                                             accP, d2min, out, N);
}